// Round 14
// baseline (436.250 us; speedup 1.0000x reference)
//
#include <hip/hip_runtime.h>
#include <math.h>
#include <type_traits>

#define WID 1024
#define HEI 1024
#define OUTC 48      // output cols per wave
#define HALOC 8      // halo lanes each side (supports K<=7)
#define BH 32        // output rows per wave
#define CB 22        // col bands: 21*48 + 16 = 1024
#define RB 32        // row bands: 8 XCD stripes * 4 warps

__device__ __forceinline__ float lane_up1(float v) {   // lane i <- lane i-1
    return __int_as_float(__builtin_amdgcn_update_dpp(
        __float_as_int(v), __float_as_int(v), 0x138, 0xF, 0xF, false)); // wave_shr:1
}
__device__ __forceinline__ float lane_dn1(float v) {   // lane i <- lane i+1
    return __int_as_float(__builtin_amdgcn_update_dpp(
        __float_as_int(v), __float_as_int(v), 0x130, 0xF, 0xF, false)); // wave_shl:1
}
__device__ __forceinline__ float fmin3(float a, float b, float c) {
    float d; asm("v_min3_f32 %0, %1, %2, %3" : "=v"(d) : "v"(a), "v"(b), "v"(c));
    return d;
}
__device__ __forceinline__ float fmax3(float a, float b, float c) {
    float d; asm("v_max3_f32 %0, %1, %2, %3" : "=v"(d) : "v"(a), "v"(b), "v"(c));
    return d;
}

// structural compile-time for: guarantees full unrolling (advisory pragma failed r13)
template<int I, int N, typename F>
__device__ __forceinline__ void sfor(F&& f) {
    if constexpr (I <= N) {
        f(std::integral_constant<int, I>{});
        sfor<I + 1, N>(static_cast<F&&>(f));
    }
}

// 8-rows-per-step fused pipeline; every row index is a compile-time constant.
// F >= K+2 (cone tightness) and F == -K (mod 8) (store alignment).
template<int K, bool FIRST, bool WIMG, bool EDGE>
__device__ __forceinline__ void body8(const float* __restrict__ imgp,
                                      float* __restrict__ outi,
                                      float* __restrict__ outs,
                                      int r0, int x, int xc, bool colIn, bool outLane)
{
    constexpr int F     = K + 2 + ((14 - 2*K) % 8 + 8) % 8;  // 9 (K=7), 10 (K=6)
    constexpr int NS0   = (F + K + 8) / 8;                   // first store step (3)
    constexpr int NSTEP = (F + K + 32) / 8;                  // 6
    const float INF = INFINITY;

    float c[K+1], d[K+1], sk[16];
    #pragma unroll
    for (int j = 0; j <= K; ++j) { c[j] = INF; d[j] = INF; }
    #pragma unroll
    for (int t = 0; t < 16; ++t) sk[t] = 0.f;

    float vI[8], vS[8] = {0.f,0.f,0.f,0.f,0.f,0.f,0.f,0.f};

    // prime img loads: rows consumed at step 1 (rr = 1-F+q)
    #pragma unroll
    for (int q = 0; q < 8; ++q) {
        const int rr = 1 - F + q;
        if (EDGE) {
            int row = r0 + rr;
            bool rin = (unsigned)row < (unsigned)HEI;
            int rowc = row < 0 ? 0 : (row > HEI-1 ? HEI-1 : row);
            float v = imgp[(size_t)rowc * WID + xc];
            vI[q] = (rin && colIn) ? v : INF;
        } else {
            vI[q] = imgp[(size_t)(r0 + rr) * WID + x];
        }
    }

    sfor<1, NSTEP>([&](auto nc) {
        constexpr int n = nc.value;

        // ---- stage-0 buffer: rows 8n-F-9 .. 8n-F ----
        float bp[10] = { c[0], d[0], vI[0], vI[1], vI[2], vI[3],
                         vI[4], vI[5], vI[6], vI[7] };
        c[0] = bp[8]; d[0] = bp[9];

        // ---- entering skel rows: rrE = 8n-F-9+q ----
        #pragma unroll
        for (int q = 0; q < 8; ++q) {
            constexpr_workaround: ;
            const int rrE = 8*n - F - 9 + q;
            if (rrE >= 0 && rrE < BH) sk[rrE & 15] = FIRST ? 0.f : vS[q];
        }

        // ---- prefetch loads for step n+1 ----
        if constexpr (n < NSTEP) {
            #pragma unroll
            for (int q = 0; q < 8; ++q) {
                const int rr = 8*(n+1) - F - 7 + q;
                if (EDGE) {
                    int row = r0 + rr;
                    bool rin = (unsigned)row < (unsigned)HEI;
                    int rowc = row < 0 ? 0 : (row > HEI-1 ? HEI-1 : row);
                    float v = imgp[(size_t)rowc * WID + xc];
                    vI[q] = (rin && colIn) ? v : INF;
                } else {
                    vI[q] = imgp[(size_t)(r0 + rr) * WID + x];
                }
            }
            if constexpr (!FIRST) {
                #pragma unroll
                for (int q = 0; q < 8; ++q) {
                    const int rrL = 8*(n+1) - F - 9 + q;
                    if (rrL >= 0 && rrL < BH)
                        vS[q] = EDGE ? outs[(size_t)(r0 + rrL) * WID + xc]
                                     : outs[(size_t)(r0 + rrL) * WID + x];
                }
            }
        }

        // ---- stages j=1..K, each followed by op t=j-1; stores folded into j==K ----
        sfor<1, K>([&](auto jc) {
            constexpr int j = jc.value;
            float bc[10];
            bc[0] = c[j]; bc[1] = d[j];
            #pragma unroll
            for (int q = 0; q < 8; ++q) {
                float up = bp[q], ce = bp[q+1], dn = bp[q+2];
                float lf = lane_up1(ce), rt = lane_dn1(ce);
                float pre = fmin3(up, ce, lf);
                float nj  = fmin3(pre, rt, dn);
                if (EDGE) {
                    const int rr = 8*n - F - 7 - j + q;
                    bool rin = (unsigned)(r0 + rr) < (unsigned)HEI;
                    nj = (rin && colIn) ? nj : INF;
                }
                bc[2+q] = nj;
            }
            c[j] = bc[8]; d[j] = bc[9];

            // op t = j-1: output rows rr = 8n-F-9-t+q; e1 = bp[q]; dilate over bc
            constexpr int t = j - 1;
            #pragma unroll
            for (int q = 0; q < 8; ++q) {
                const int rr = 8*n - F - 9 - t + q;
                float a0 = bc[q], a1 = bc[q+1], a2 = bc[q+2];
                if (EDGE) {
                    bool i0 = (unsigned)(r0 + rr - 1) < (unsigned)HEI;
                    bool i1 = (unsigned)(r0 + rr    ) < (unsigned)HEI;
                    bool i2 = (unsigned)(r0 + rr + 1) < (unsigned)HEI;
                    a0 = i0 ? a0 : -INF;
                    a1 = i1 ? a1 : -INF;
                    a2 = i2 ? a2 : -INF;
                }
                float vm = fmax3(a0, a1, a2);
                if (EDGE) vm = colIn ? vm : -INF;
                float hl = lane_up1(vm), hr = lane_dn1(vm);
                float dd = fmax3(hl, hr, vm);
                float delta = fmaxf(bp[q] - dd, 0.f);
                float sv = sk[rr & 15];
                sk[rr & 15] = sv + fmaf(-sv, delta, delta);
            }

            if constexpr (j < K) {
                #pragma unroll
                for (int p = 0; p < 10; ++p) bp[p] = bc[p];
            } else if constexpr (n >= NS0) {
                // stores: rows rr = 8(n-NS0)+q; skel final after op K-1 this step;
                // E^K row rr = bc[q+1] (bc[p] = row 8n-F-9-K+p, F+K+9-8*NS0 = 1+... aligned)
                #pragma unroll
                for (int q = 0; q < 8; ++q) {
                    const int rr = 8*(n - NS0) + q;
                    if (outLane) {
                        outs[(size_t)(r0 + rr) * WID + x] = sk[rr & 15];
                        if (WIMG) outi[(size_t)(r0 + rr) * WID + x] = bc[q + 1];
                    }
                }
            }
        });
    });
}

template<int K, bool FIRST, bool WIMG>
__global__ __launch_bounds__(256, 3)
void pass_kernel(const float* __restrict__ img_in, float* __restrict__ img_out,
                 float* __restrict__ skel)
{
    const int lane = threadIdx.x & 63;
    const int warp = threadIdx.x >> 6;
    // XCD swizzle: rbg = bid&7 -> XCD; each XCD owns a contiguous 128-row stripe.
    const int bid  = blockIdx.x;
    const int rbg  = bid & 7;
    const int rest = bid >> 3;
    const int cb   = rest % CB;
    const int b    = rest / CB;
    const int rb   = rbg*4 + warp;   // 0..31

    const int outc = (cb == CB-1) ? (WID - (CB-1)*OUTC) : OUTC;  // 48 or 16
    const int x0   = cb*OUTC - HALOC;
    const int r0   = rb*BH;
    const int x    = x0 + lane;
    const int xc   = x < 0 ? 0 : (x > WID-1 ? WID-1 : x);
    const bool colIn   = ((unsigned)x < (unsigned)WID);
    const bool outLane = (lane >= HALOC) && (lane < HALOC + outc);
    const size_t base = (size_t)b*HEI*WID;

    const float* imgp = img_in + base;
    float* outi = WIMG ? (img_out + base) : nullptr;
    float* outs = skel + base;

    const bool edge = (cb == 0) || (cb == CB-1) || (rb == 0) || (rb == RB-1);
    if (edge)
        body8<K, FIRST, WIMG, true >(imgp, outi, outs, r0, x, xc, colIn, outLane);
    else
        body8<K, FIRST, WIMG, false>(imgp, outi, outs, r0, x, xc, colIn, outLane);
}

extern "C" void kernel_launch(void* const* d_in, const int* in_sizes, int n_in,
                              void* d_out, int out_size, void* d_ws, size_t ws_size,
                              hipStream_t stream)
{
    const float* img = (const float*)d_in[0];
    float* skel = (float*)d_out;
    const int total = in_sizes[0];
    const int B = total / (HEI*WID);

    float* bufA = (float*)d_ws;
    float* bufB = bufA + (size_t)total;

    const int blocks = 8 * CB * B;   // 4 row-band waves per block

    // 41 ops (t=0..40): 5 passes of K=7, then K=6.
    pass_kernel<7,true, true ><<<blocks,256,0,stream>>>(img,  bufA, skel); // t=0..6
    pass_kernel<7,false,true ><<<blocks,256,0,stream>>>(bufA, bufB, skel); // t=7..13
    pass_kernel<7,false,true ><<<blocks,256,0,stream>>>(bufB, bufA, skel); // t=14..20
    pass_kernel<7,false,true ><<<blocks,256,0,stream>>>(bufA, bufB, skel); // t=21..27
    pass_kernel<7,false,true ><<<blocks,256,0,stream>>>(bufB, bufA, skel); // t=28..34
    pass_kernel<6,false,false><<<blocks,256,0,stream>>>(bufA, nullptr, skel); // t=35..40
}

// Round 15
// 165.281 us; speedup vs baseline: 2.6394x; 2.6394x over previous
//
#include <hip/hip_runtime.h>
#include <math.h>

#define WID 1024
#define HEI 1024
#define OUTC 48      // output cols per wave
#define HALOC 8      // halo lanes each side (supports K<=7)
#define BH 16        // output rows per wave
#define CB 22        // col bands: 21*48 + 16 = 1024
#define RB 64        // row bands: 8 XCD stripes * 8 bands

__device__ __forceinline__ float lane_up1(float v) {   // lane i <- lane i-1
    return __int_as_float(__builtin_amdgcn_update_dpp(
        __float_as_int(v), __float_as_int(v), 0x138, 0xF, 0xF, false)); // wave_shr:1
}
__device__ __forceinline__ float lane_dn1(float v) {   // lane i <- lane i+1
    return __int_as_float(__builtin_amdgcn_update_dpp(
        __float_as_int(v), __float_as_int(v), 0x130, 0xF, 0xF, false)); // wave_shl:1
}
__device__ __forceinline__ float fmin3(float a, float b, float c) {
    float d; asm("v_min3_f32 %0, %1, %2, %3" : "=v"(d) : "v"(a), "v"(b), "v"(c));
    return d;
}
__device__ __forceinline__ float fmax3(float a, float b, float c) {
    float d; asm("v_max3_f32 %0, %1, %2, %3" : "=v"(d) : "v"(a), "v"(b), "v"(c));
    return d;
}

// 4-rows-per-step fused pipeline (r12 structure, verified absmax=0).
// EDGE: runtime row/col masking (boundary waves). PLAIN: no masking (interior).
template<int K, bool FIRST, bool WIMG, bool EDGE>
__device__ __forceinline__ void body4(const float* __restrict__ imgp,
                                      float* __restrict__ outi,
                                      float* __restrict__ outs,
                                      int r0, int x, int xc, bool colIn, bool outLane)
{
    constexpr int FILL  = ((K & 3) == 3) ? (K + 6) : (K + 8);  // 13 (K=7), 14 (K=6)
    constexpr int NSTEP = (BH + 20) / 4;                        // 9
    const float INF = INFINITY;

    float c[K+1], d[K+1], sk[16];
    #pragma unroll
    for (int j = 0; j <= K; ++j) { c[j] = INF; d[j] = INF; }
    #pragma unroll
    for (int t = 0; t < 16; ++t) sk[t] = 0.f;

    float vI[4], vS[4] = {0.f, 0.f, 0.f, 0.f};

    // prime img loads: rows for step 1 (rr = 1-FILL+q)
    #pragma unroll
    for (int q = 0; q < 4; ++q) {
        const int rr = 1 - FILL + q;
        if (EDGE) {
            int row = r0 + rr;
            bool rin = (unsigned)row < (unsigned)HEI;
            int rowc = row < 0 ? 0 : (row > HEI-1 ? HEI-1 : row);
            float v = imgp[(size_t)rowc * WID + xc];
            vI[q] = (rin && colIn) ? v : INF;
        } else {
            vI[q] = imgp[(size_t)(r0 + rr) * WID + x];
        }
    }

    #pragma unroll
    for (int n = 1; n <= NSTEP; ++n) {
        // ---- stage-0 buffer: rows 4n-FILL-5 .. 4n-FILL (c,d,new0..3) ----
        float bp[6] = { c[0], d[0], vI[0], vI[1], vI[2], vI[3] };
        c[0] = bp[4]; d[0] = bp[5];

        // ---- entering skel rows (op-0 window this step) ----
        #pragma unroll
        for (int q = 0; q < 4; ++q) {
            const int rrE = 4*n - FILL - 5 + q;
            if (rrE >= 0 && rrE < BH) sk[rrE & 15] = FIRST ? 0.f : vS[q];
        }

        // ---- prefetch loads for step n+1 ----
        if (n < NSTEP) {
            #pragma unroll
            for (int q = 0; q < 4; ++q) {
                const int rr = 4*(n+1) - FILL - 3 + q;
                if (EDGE) {
                    int row = r0 + rr;
                    bool rin = (unsigned)row < (unsigned)HEI;
                    int rowc = row < 0 ? 0 : (row > HEI-1 ? HEI-1 : row);
                    float v = imgp[(size_t)rowc * WID + xc];
                    vI[q] = (rin && colIn) ? v : INF;
                } else {
                    vI[q] = imgp[(size_t)(r0 + rr) * WID + x];
                }
            }
            if (!FIRST) {
                #pragma unroll
                for (int q = 0; q < 4; ++q) {
                    const int rrL = 4*(n+1) - FILL - 5 + q;
                    if (rrL >= 0 && rrL < BH)
                        vS[q] = EDGE ? outs[(size_t)(r0 + rrL) * WID + xc]
                                     : outs[(size_t)(r0 + rrL) * WID + x];
                }
            }
        }

        float eK[6];

        // ---- stages j=1..K, each followed by op t=j-1 ----
        #pragma unroll
        for (int j = 1; j <= K; ++j) {
            float o[4];
            #pragma unroll
            for (int q = 0; q < 4; ++q) {
                float up = bp[q], ce = bp[q+1], dn = bp[q+2];
                float lf = lane_up1(ce), rt = lane_dn1(ce);
                float pre = fmin3(up, ce, lf);
                float nj  = fmin3(pre, rt, dn);
                if (EDGE) {
                    const int rr = 4*n - FILL - 3 - j + q;
                    bool rin = (unsigned)(r0 + rr) < (unsigned)HEI;
                    nj = (rin && colIn) ? nj : INF;
                }
                o[q] = nj;
            }
            float bc[6] = { c[j], d[j], o[0], o[1], o[2], o[3] };
            c[j] = bc[4]; d[j] = bc[5];

            // op t = j-1: output rows rr = 4n-FILL-5-t+q, e1 = bp[q], dilate over bc
            {
                const int t = j - 1;
                #pragma unroll
                for (int q = 0; q < 4; ++q) {
                    const int rr = 4*n - FILL - 5 - t + q;
                    float a0 = bc[q], a1 = bc[q+1], a2 = bc[q+2];
                    if (EDGE) {
                        bool i0 = (unsigned)(r0 + rr - 1) < (unsigned)HEI;
                        bool i1 = (unsigned)(r0 + rr    ) < (unsigned)HEI;
                        bool i2 = (unsigned)(r0 + rr + 1) < (unsigned)HEI;
                        a0 = i0 ? a0 : -INF;
                        a1 = i1 ? a1 : -INF;
                        a2 = i2 ? a2 : -INF;
                    }
                    float vm = fmax3(a0, a1, a2);
                    if (EDGE) vm = colIn ? vm : -INF;
                    float hl = lane_up1(vm), hr = lane_dn1(vm);
                    float dd = fmax3(hl, hr, vm);
                    float delta = fmaxf(bp[q] - dd, 0.f);
                    float sv = sk[rr & 15];
                    sk[rr & 15] = sv + fmaf(-sv, delta, delta);
                }
            }
            #pragma unroll
            for (int p = 0; p < 6; ++p) bp[p] = bc[p];
            if (j == K) {
                #pragma unroll
                for (int p = 0; p < 6; ++p) eK[p] = bc[p];
            }
        }

        // ---- stores: rows 4n-24+q (skel final after op K-1; E^K = eK[1+q]) ----
        #pragma unroll
        for (int q = 0; q < 4; ++q) {
            const int rr = 4*n - 24 + q;
            if (rr >= 0 && rr < BH) {
                if (outLane) outs[(size_t)(r0 + rr) * WID + x] = sk[rr & 15];
                if (WIMG) { if (outLane) outi[(size_t)(r0 + rr) * WID + x] = eK[1 + q]; }
            }
        }
    }
}

template<int K, bool FIRST, bool WIMG>
__global__ __launch_bounds__(256, 3)
void pass_kernel(const float* __restrict__ img_in, float* __restrict__ img_out,
                 float* __restrict__ skel)
{
    const int lane = threadIdx.x & 63;
    const int warp = threadIdx.x >> 6;
    // XCD swizzle: rbg = bid&7 -> XCD; each XCD owns a contiguous 128-row stripe
    // (8 bands of 16 rows); 2 blocks (sub) per stripe per col-band.
    const int bid   = blockIdx.x;
    const int rbg   = bid & 7;
    const int rest  = bid >> 3;
    const int sub   = rest & 1;
    const int rest2 = rest >> 1;
    const int cb    = rest2 % CB;
    const int b     = rest2 / CB;
    const int rb    = rbg*8 + sub*4 + warp;   // 0..63

    const int outc = (cb == CB-1) ? (WID - (CB-1)*OUTC) : OUTC;  // 48 or 16
    const int x0   = cb*OUTC - HALOC;
    const int r0   = rb*BH;
    const int x    = x0 + lane;
    const int xc   = x < 0 ? 0 : (x > WID-1 ? WID-1 : x);
    const bool colIn   = ((unsigned)x < (unsigned)WID);
    const bool outLane = (lane >= HALOC) && (lane < HALOC + outc);
    const size_t base = (size_t)b*HEI*WID;

    const float* imgp = img_in + base;
    float* outi = WIMG ? (img_out + base) : nullptr;
    float* outs = skel + base;

    const bool edge = (cb == 0) || (cb == CB-1) || (rb == 0) || (rb == RB-1);
    if (edge)
        body4<K, FIRST, WIMG, true >(imgp, outi, outs, r0, x, xc, colIn, outLane);
    else
        body4<K, FIRST, WIMG, false>(imgp, outi, outs, r0, x, xc, colIn, outLane);
}

extern "C" void kernel_launch(void* const* d_in, const int* in_sizes, int n_in,
                              void* d_out, int out_size, void* d_ws, size_t ws_size,
                              hipStream_t stream)
{
    const float* img = (const float*)d_in[0];
    float* skel = (float*)d_out;
    const int total = in_sizes[0];
    const int B = total / (HEI*WID);

    float* bufA = (float*)d_ws;
    float* bufB = bufA + (size_t)total;

    const int blocks = 8 * 2 * CB * B;   // 4 row-band waves per block

    // 41 ops (t=0..40): 5 passes of K=7, then K=6.
    pass_kernel<7,true, true ><<<blocks,256,0,stream>>>(img,  bufA, skel); // t=0..6
    pass_kernel<7,false,true ><<<blocks,256,0,stream>>>(bufA, bufB, skel); // t=7..13
    pass_kernel<7,false,true ><<<blocks,256,0,stream>>>(bufB, bufA, skel); // t=14..20
    pass_kernel<7,false,true ><<<blocks,256,0,stream>>>(bufA, bufB, skel); // t=21..27
    pass_kernel<7,false,true ><<<blocks,256,0,stream>>>(bufB, bufA, skel); // t=28..34
    pass_kernel<6,false,false><<<blocks,256,0,stream>>>(bufA, nullptr, skel); // t=35..40
}